// Round 3
// baseline (205.176 us; speedup 1.0000x reference)
//
#include <hip/hip_runtime.h>
#include <math.h>

// Normalization_60095182406123
//
// Separable 4D Gaussian filter of x^2 over axes (freq, orient, y, x):
//   out[c,y,x] = sum g3[df] g3[do] g32[dy] g32[dx] * xsq[c+(df-1)*16+(do-1)*2, y+dy-16, x+dx-16]
// c = img*192 + freq*16 + orient*2 + phase (same flat layout in and out).
//
// Pass 1: x^2 + orient(3) + freq(3) + blur_x(32) -> ws[c,y,x]
//   - freq axis split 3-way (4 output freqs + 1 halo each side)
//   - x axis split 2-way (112 outputs + 16/15 halo = 143-float span)
//   - LDS 48 rows x 148 floats = 28,416 B -> 4 blocks/CU (wave-slot capped), 32 waves/CU
// Pass 2: blur_y(32) -> out[c,y,x]
//
// ws needs 768*224*224*4 = 154,140,672 bytes of d_ws.

#define SZW   224
#define PLANE (224*224)
#define PWH   148          // LDS row width in floats (143-float window + pad)
#define XH    112          // output columns per block

#define INV_SQRT_2PI 0.3989422804014327f

__global__ __launch_bounds__(512, 6) void pass1_kernel(const float* __restrict__ in,
                                                       float* __restrict__ ws)
{
    __shared__ float s2[48 * PWH];   // 28,416 B

    const int tid   = threadIdx.x;
    const int y     = blockIdx.x;          // 0..223
    const int by    = blockIdx.y;          // 0..11
    const int xh    = by & 1;              // x half
    const int phase = (by >> 1) & 1;
    const int fg    = by >> 2;             // freq group: output f in [4fg, 4fg+4)
    const int img   = blockIdx.z;          // 0..3

    const int xb = xh * XH;                // output x base (0 or 112)
    const int lo = xh ? 96 : 0;            // global x of the 128-float aligned load run
    const int d0 = xh ? 0  : 16;           // LDS dst offset of that run

    const float w31 = INV_SQRT_2PI;                 // g3 center
    const float w30 = INV_SQRT_2PI * expf(-0.5f);   // g3 edge

    // ---- step 1: load x^2 (x window), orient 3-tap, to LDS; zero-fill pads ----
    if (tid < 384) {
        const int lf  = tid >> 6;          // 0..5
        const int xp4 = tid & 63;
        const int f   = 4*fg - 1 + lf;     // -1..12
        if (xp4 < 32) {
            float4 a[8];
            if (f >= 0 && f < 12) {
                const float* base = in + (size_t)(img*192 + f*16 + phase)*PLANE
                                       + y*SZW + lo + xp4*4;
                #pragma unroll
                for (int o = 0; o < 8; ++o) {
                    float4 v = *reinterpret_cast<const float4*>(base + o*2*PLANE);
                    a[o] = make_float4(v.x*v.x, v.y*v.y, v.z*v.z, v.w*v.w);
                }
            } else {
                #pragma unroll
                for (int o = 0; o < 8; ++o) a[o] = make_float4(0.f,0.f,0.f,0.f);
            }
            #pragma unroll
            for (int o = 0; o < 8; ++o) {
                float4 l = (o > 0) ? a[o-1] : make_float4(0.f,0.f,0.f,0.f);
                float4 r = (o < 7) ? a[o+1] : make_float4(0.f,0.f,0.f,0.f);
                float4 b;
                b.x = fmaf(w31, a[o].x, w30*(l.x + r.x));
                b.y = fmaf(w31, a[o].y, w30*(l.y + r.y));
                b.z = fmaf(w31, a[o].z, w30*(l.z + r.z));
                b.w = fmaf(w31, a[o].w, w30*(l.w + r.w));
                *reinterpret_cast<float4*>(&s2[(lf*8 + o)*PWH + d0 + xp4*4]) = b;
            }
        } else if (xp4 < 37) {
            // 5 zero groups per row: xh=0 -> {0,1,2,3,36}; xh=1 -> {32,33,34,35,36}
            const int zi = xp4 - 32;
            const int g  = xh ? (32 + zi) : (zi < 4 ? zi : 36);
            #pragma unroll
            for (int o = 0; o < 8; ++o)
                *reinterpret_cast<float4*>(&s2[(lf*8 + o)*PWH + g*4]) =
                    make_float4(0.f,0.f,0.f,0.f);
        }
    }
    __syncthreads();

    // ---- step 2: freq 3-tap conv in place (thread owns its (o, group) column) ----
    {
        const int o   = tid >> 6;          // 0..7
        const int xp4 = tid & 63;
        if (xp4 < 37) {
            float4 a[6];
            #pragma unroll
            for (int lf = 0; lf < 6; ++lf)
                a[lf] = *reinterpret_cast<const float4*>(&s2[(lf*8 + o)*PWH + xp4*4]);
            #pragma unroll
            for (int lf = 1; lf < 5; ++lf) {
                float4 b;
                b.x = fmaf(w31, a[lf].x, w30*(a[lf-1].x + a[lf+1].x));
                b.y = fmaf(w31, a[lf].y, w30*(a[lf-1].y + a[lf+1].y));
                b.z = fmaf(w31, a[lf].z, w30*(a[lf-1].z + a[lf+1].z));
                b.w = fmaf(w31, a[lf].w, w30*(a[lf-1].w + a[lf+1].w));
                *reinterpret_cast<float4*>(&s2[(lf*8 + o)*PWH + xp4*4]) = b;
            }
        }
    }
    __syncthreads();

    // ---- step 3: 32-tap blur along x, write ws ----
    float wx[32];
    #pragma unroll
    for (int k = 0; k < 32; ++k) {
        float t = fmaf((float)k, 2.0f/31.0f, -1.0f);
        wx[k] = INV_SQRT_2PI * expf(-0.5f*t*t);
    }

    const int obase = (img*192 + phase)*PLANE + y*SZW + xb;

    // units: 32 output rows (lf 1..4, o 0..7) x 28 float4 groups = 896
    for (int u = tid; u < 32*28; u += 512) {
        const int r  = u / 28;             // 0..31
        const int xq = u - r*28;
        const int lf = 1 + (r >> 3);
        const int o  = r & 7;
        const int fo16 = (4*fg + (r >> 3))*16 + o*2;
        const int x0 = xq * 4;             // local output x (0..108)
        const float4* p = reinterpret_cast<const float4*>(&s2[(lf*8 + o)*PWH + x0]);
        float acc0 = 0.f, acc1 = 0.f, acc2 = 0.f, acc3 = 0.f;
        #pragma unroll
        for (int t = 0; t < 9; ++t) {
            float4 q = p[t];
            #pragma unroll
            for (int j = 0; j < 4; ++j) {
                const int m = 4*t + j;     // window index 0..35
                const float qv = (j==0)?q.x:(j==1)?q.y:(j==2)?q.z:q.w;
                if (m - 0 >= 0 && m - 0 < 32) acc0 = fmaf(wx[m-0], qv, acc0);
                if (m - 1 >= 0 && m - 1 < 32) acc1 = fmaf(wx[m-1], qv, acc1);
                if (m - 2 >= 0 && m - 2 < 32) acc2 = fmaf(wx[m-2], qv, acc2);
                if (m - 3 >= 0 && m - 3 < 32) acc3 = fmaf(wx[m-3], qv, acc3);
            }
        }
        *reinterpret_cast<float4*>(ws + obase + fo16*PLANE + x0) =
            make_float4(acc0, acc1, acc2, acc3);
    }
}

__global__ __launch_bounds__(256) void pass2_kernel(const float* __restrict__ ws,
                                                    float* __restrict__ out)
{
    const int c = blockIdx.x;     // 0..767
    const int x = threadIdx.x;    // column
    if (x >= SZW) return;

    float wy[32];
    #pragma unroll
    for (int k = 0; k < 32; ++k) {
        float t = fmaf((float)k, 2.0f/31.0f, -1.0f);
        wy[k] = INV_SQRT_2PI * expf(-0.5f*t*t);
    }

    const float* col = ws  + c * PLANE + x;
    float*       oc  = out + c * PLANE + x;

    float w[47];
    #pragma unroll
    for (int i = 0; i < 47; ++i) {
        int yy = i - 16;
        w[i] = (yy >= 0 && yy < SZW) ? col[yy*SZW] : 0.f;
    }

    #pragma unroll 1
    for (int y0 = 0; y0 < SZW; y0 += 16) {
        float acc[16];
        #pragma unroll
        for (int j = 0; j < 16; ++j) acc[j] = 0.f;
        #pragma unroll
        for (int k = 0; k < 32; ++k) {
            #pragma unroll
            for (int j = 0; j < 16; ++j)
                acc[j] = fmaf(wy[k], w[j+k], acc[j]);
        }
        #pragma unroll
        for (int j = 0; j < 16; ++j) oc[(y0+j)*SZW] = acc[j];

        #pragma unroll
        for (int i = 0; i < 31; ++i) w[i] = w[i+16];
        #pragma unroll
        for (int i = 0; i < 16; ++i) {
            int yy = y0 + 31 + i;
            w[31+i] = (yy < SZW) ? col[yy*SZW] : 0.f;
        }
    }
}

extern "C" void kernel_launch(void* const* d_in, const int* in_sizes, int n_in,
                              void* d_out, int out_size, void* d_ws, size_t ws_size,
                              hipStream_t stream)
{
    const float* x  = (const float*)d_in[0];
    float*      out = (float*)d_out;
    float*      ws  = (float*)d_ws;   // 768*224*224*4 = 154,140,672 B

    dim3 g1(SZW, 12, 4);              // (y, xhalf*phase*freqgroup, img)
    pass1_kernel<<<g1, 512, 0, stream>>>(x, ws);
    pass2_kernel<<<768, 256, 0, stream>>>(ws, out);
}

// Round 4
// 181.814 us; speedup vs baseline: 1.1285x; 1.1285x over previous
//
#include <hip/hip_runtime.h>
#include <math.h>

// Normalization_60095182406123
//
// Separable 4D Gaussian filter of x^2 over axes (freq, orient, y, x):
//   out[c,y,x] = sum g3[df] g3[do] g32[dy] g32[dx] * xsq[c+(df-1)*16+(do-1)*2, y+dy-16, x+dx-16]
// c = img*192 + freq*16 + orient*2 + phase (same flat layout in and out).
//
// Pass 1: x^2 + orient(3) + freq(3) + blur_x(32) -> ws[c,y,x]
//   - freq axis split 4-way (3 output freqs + 1 halo each side = 5 staged)
//   - LDS 40 rows x 256 floats = 40,960 B -> exactly 4 blocks/CU, 32 waves/CU
//   - Gaussian weights passed as kernel args (host-computed, no expf in kernel)
// Pass 2: blur_y(32) -> out[c,y,x]
//
// ws needs 768*224*224*4 = 154,140,672 bytes of d_ws.

#define SZW   224
#define PLANE (224*224)
#define PW    256          // LDS row: 16 zero | 224 data | 15 zero | 1 spare

struct GaussArgs {
    float wx[32];   // 32-tap Gaussian (l=32, w=1), matches reference _gauss
    float w30;      // 3-tap edge   = c*exp(-0.5)
    float w31;      // 3-tap center = c
};

__global__ __launch_bounds__(512, 8) void pass1_kernel(const float* __restrict__ in,
                                                       float* __restrict__ ws,
                                                       const GaussArgs ga)
{
    __shared__ float s2[40 * PW];   // 40,960 B

    const int tid   = threadIdx.x;
    const int y     = blockIdx.x;          // 0..223
    const int by    = blockIdx.y;          // 0..7
    const int phase = by & 1;
    const int fg    = by >> 1;             // freq group: output f in [3fg, 3fg+3)
    const int img   = blockIdx.z;          // 0..3

    const float w31 = ga.w31;
    const float w30 = ga.w30;

    // ---- step 1: load x^2 (x-padded), orient 3-tap conv in regs, to LDS ----
    // 5 staged freqs lf=0..4 -> f = 3fg-1+lf; 64 float4 groups per row.
    if (tid < 320) {
        const int lf  = tid >> 6;          // 0..4
        const int xp4 = tid & 63;
        const int f   = 3*fg - 1 + lf;     // -1..12
        float4 a[8];
        if (f >= 0 && f < 12 && xp4 >= 4 && xp4 < 60) {
            const int x0 = xp4*4 - 16;     // 0..220, 16B-aligned
            const float* base = in + (size_t)(img*192 + f*16 + phase)*PLANE + y*SZW + x0;
            #pragma unroll
            for (int o = 0; o < 8; ++o) {
                float4 v = *reinterpret_cast<const float4*>(base + o*2*PLANE);
                a[o] = make_float4(v.x*v.x, v.y*v.y, v.z*v.z, v.w*v.w);
            }
        } else {
            #pragma unroll
            for (int o = 0; o < 8; ++o) a[o] = make_float4(0.f,0.f,0.f,0.f);
        }
        #pragma unroll
        for (int o = 0; o < 8; ++o) {
            float4 l = (o > 0) ? a[o-1] : make_float4(0.f,0.f,0.f,0.f);
            float4 r = (o < 7) ? a[o+1] : make_float4(0.f,0.f,0.f,0.f);
            float4 b;
            b.x = fmaf(w31, a[o].x, w30*(l.x + r.x));
            b.y = fmaf(w31, a[o].y, w30*(l.y + r.y));
            b.z = fmaf(w31, a[o].z, w30*(l.z + r.z));
            b.w = fmaf(w31, a[o].w, w30*(l.w + r.w));
            *reinterpret_cast<float4*>(&s2[(lf*8 + o)*PW + xp4*4]) = b;
        }
    }
    __syncthreads();

    // ---- step 2: freq 3-tap conv in place (thread owns its (o, xp4) column) ----
    {
        const int o   = tid >> 6;          // 0..7
        const int xp4 = tid & 63;
        float4 a[5];
        #pragma unroll
        for (int lf = 0; lf < 5; ++lf)
            a[lf] = *reinterpret_cast<const float4*>(&s2[(lf*8 + o)*PW + xp4*4]);
        #pragma unroll
        for (int lf = 1; lf < 4; ++lf) {
            float4 b;
            b.x = fmaf(w31, a[lf].x, w30*(a[lf-1].x + a[lf+1].x));
            b.y = fmaf(w31, a[lf].y, w30*(a[lf-1].y + a[lf+1].y));
            b.z = fmaf(w31, a[lf].z, w30*(a[lf-1].z + a[lf+1].z));
            b.w = fmaf(w31, a[lf].w, w30*(a[lf-1].w + a[lf+1].w));
            *reinterpret_cast<float4*>(&s2[(lf*8 + o)*PW + xp4*4]) = b;
        }
    }
    __syncthreads();

    // ---- step 3: 32-tap blur along x, write ws ----
    const int obase = (img*192 + phase)*PLANE + y*SZW;

    // units: 24 output rows (lf 1..3, o 0..7) x 56 float4 groups = 1344
    for (int u = tid; u < 24*56; u += 512) {
        const int r  = u / 56;             // 0..23
        const int xq = u - r*56;
        const int lf = 1 + (r >> 3);
        const int o  = r & 7;
        const int fo16 = (3*fg + (r >> 3))*16 + o*2;
        const int x0 = xq * 4;             // output x (0..220)
        const float4* p = reinterpret_cast<const float4*>(&s2[(lf*8 + o)*PW + x0]);
        float acc0 = 0.f, acc1 = 0.f, acc2 = 0.f, acc3 = 0.f;
        #pragma unroll
        for (int t = 0; t < 9; ++t) {
            float4 q = p[t];
            #pragma unroll
            for (int j = 0; j < 4; ++j) {
                const int m = 4*t + j;     // window index 0..35
                const float qv = (j==0)?q.x:(j==1)?q.y:(j==2)?q.z:q.w;
                if (m - 0 >= 0 && m - 0 < 32) acc0 = fmaf(ga.wx[m-0], qv, acc0);
                if (m - 1 >= 0 && m - 1 < 32) acc1 = fmaf(ga.wx[m-1], qv, acc1);
                if (m - 2 >= 0 && m - 2 < 32) acc2 = fmaf(ga.wx[m-2], qv, acc2);
                if (m - 3 >= 0 && m - 3 < 32) acc3 = fmaf(ga.wx[m-3], qv, acc3);
            }
        }
        *reinterpret_cast<float4*>(ws + obase + fo16*PLANE + x0) =
            make_float4(acc0, acc1, acc2, acc3);
    }
}

__global__ __launch_bounds__(256) void pass2_kernel(const float* __restrict__ ws,
                                                    float* __restrict__ out,
                                                    const GaussArgs ga)
{
    const int c = blockIdx.x;     // 0..767
    const int x = threadIdx.x;    // column
    if (x >= SZW) return;

    const float* col = ws  + c * PLANE + x;
    float*       oc  = out + c * PLANE + x;

    float w[47];
    #pragma unroll
    for (int i = 0; i < 47; ++i) {
        int yy = i - 16;
        w[i] = (yy >= 0 && yy < SZW) ? col[yy*SZW] : 0.f;
    }

    #pragma unroll 1
    for (int y0 = 0; y0 < SZW; y0 += 16) {
        float acc[16];
        #pragma unroll
        for (int j = 0; j < 16; ++j) acc[j] = 0.f;
        #pragma unroll
        for (int k = 0; k < 32; ++k) {
            #pragma unroll
            for (int j = 0; j < 16; ++j)
                acc[j] = fmaf(ga.wx[k], w[j+k], acc[j]);
        }
        #pragma unroll
        for (int j = 0; j < 16; ++j) oc[(y0+j)*SZW] = acc[j];

        #pragma unroll
        for (int i = 0; i < 31; ++i) w[i] = w[i+16];
        #pragma unroll
        for (int i = 0; i < 16; ++i) {
            int yy = y0 + 31 + i;
            w[31+i] = (yy < SZW) ? col[yy*SZW] : 0.f;
        }
    }
}

extern "C" void kernel_launch(void* const* d_in, const int* in_sizes, int n_in,
                              void* d_out, int out_size, void* d_ws, size_t ws_size,
                              hipStream_t stream)
{
    const float* x  = (const float*)d_in[0];
    float*      out = (float*)d_out;
    float*      ws  = (float*)d_ws;   // 768*224*224*4 = 154,140,672 B

    // Host-computed Gaussian weights, double precision then rounded to f32
    // (matches reference _gauss: float64 linspace/exp -> astype(float32)).
    GaussArgs ga;
    const double c0 = 1.0 / sqrt(2.0 * 3.14159265358979323846);
    for (int k = 0; k < 32; ++k) {
        double t = -1.0 + 2.0 * (double)k / 31.0;
        ga.wx[k] = (float)(c0 * exp(-t * t / 2.0));
    }
    ga.w31 = (float)c0;
    ga.w30 = (float)(c0 * exp(-0.5));

    dim3 g1(SZW, 8, 4);               // (y, phase*freqgroup, img)
    pass1_kernel<<<g1, 512, 0, stream>>>(x, ws, ga);
    pass2_kernel<<<768, 256, 0, stream>>>(ws, out, ga);
}

// Round 5
// 154.760 us; speedup vs baseline: 1.3258x; 1.1748x over previous
//
#include <hip/hip_runtime.h>
#include <math.h>

// Normalization_60095182406123
//
// Separable 4D Gaussian filter of x^2 over axes (freq, orient, y, x):
//   out[c,y,x] = sum g3[df] g3[do] g32[dy] g32[dx] * xsq[c+(df-1)*16+(do-1)*2, y+dy-16, x+dx-16]
// c = img*192 + freq*16 + orient*2 + phase (same flat layout in and out).
//
// Pass 1: x^2 + orient(3) + freq(3) + blur_x(32) -> ws[c,y,x]
//   - freq split 3-way (4 output freqs + 1 halo each side = 6 staged)
//   - LDS 48 rows x 256 floats = 49,152 B -> 3 blocks/CU
//   - step 3 does 16 outputs/thread (12 ds_read_b128 per 16 outs, was 9 per 4)
//   - within-row XOR group swizzle g^=(g>>3)&7 breaks the stride-64B bank pattern
//   - Gaussian weights host-computed, passed as kernel args
// Pass 2: blur_y(32) -> out[c,y,x]
//
// ws needs 768*224*224*4 = 154,140,672 bytes of d_ws.

#define SZW   224
#define PLANE (224*224)
#define PW    256          // floats per LDS row: 16 zero | 224 data | 15 zero | 1 spare

struct GaussArgs {
    float wx[32];   // 32-tap Gaussian (l=32, w=1), matches reference _gauss
    float w30;      // 3-tap edge   = c*exp(-0.5)
    float w31;      // 3-tap center = c
};

// within-row float4-group swizzle (involution, preserves 8-group blocks)
__device__ __forceinline__ int swz(int g) { return g ^ ((g >> 3) & 7); }

__global__ __launch_bounds__(512, 6) void pass1_kernel(const float* __restrict__ in,
                                                       float* __restrict__ ws,
                                                       const GaussArgs ga)
{
    __shared__ float s2[48 * PW];   // 49,152 B

    const int tid   = threadIdx.x;
    const int y     = blockIdx.x;          // 0..223
    const int by    = blockIdx.y;          // 0..5
    const int phase = by & 1;
    const int fg    = by >> 1;             // freq group: output f in [4fg, 4fg+4)
    const int img   = blockIdx.z;          // 0..3

    const float w31 = ga.w31;
    const float w30 = ga.w30;

    // ---- step 1: load x^2 (x-padded), orient 3-tap conv in regs, to LDS ----
    // 6 staged freqs lf=0..5 -> f = 4fg-1+lf; 64 float4 groups per row.
    if (tid < 384) {
        const int lf  = tid >> 6;          // 0..5
        const int xp4 = tid & 63;
        const int f   = 4*fg - 1 + lf;     // -1..12
        const int gsw = swz(xp4);
        float4 a[8];
        if (f >= 0 && f < 12 && xp4 >= 4 && xp4 < 60) {
            const int x0 = xp4*4 - 16;     // 0..220, 16B-aligned
            const float* base = in + (size_t)(img*192 + f*16 + phase)*PLANE + y*SZW + x0;
            #pragma unroll
            for (int o = 0; o < 8; ++o) {
                float4 v = *reinterpret_cast<const float4*>(base + o*2*PLANE);
                a[o] = make_float4(v.x*v.x, v.y*v.y, v.z*v.z, v.w*v.w);
            }
        } else {
            #pragma unroll
            for (int o = 0; o < 8; ++o) a[o] = make_float4(0.f,0.f,0.f,0.f);
        }
        #pragma unroll
        for (int o = 0; o < 8; ++o) {
            float4 l = (o > 0) ? a[o-1] : make_float4(0.f,0.f,0.f,0.f);
            float4 r = (o < 7) ? a[o+1] : make_float4(0.f,0.f,0.f,0.f);
            float4 b;
            b.x = fmaf(w31, a[o].x, w30*(l.x + r.x));
            b.y = fmaf(w31, a[o].y, w30*(l.y + r.y));
            b.z = fmaf(w31, a[o].z, w30*(l.z + r.z));
            b.w = fmaf(w31, a[o].w, w30*(l.w + r.w));
            *reinterpret_cast<float4*>(&s2[(lf*8 + o)*PW + gsw*4]) = b;
        }
    }
    __syncthreads();

    // ---- step 2: freq 3-tap conv in place (thread owns its (o, xp4) column) ----
    {
        const int o   = tid >> 6;          // 0..7
        const int xp4 = tid & 63;
        const int gsw = swz(xp4);
        float4 a[6];
        #pragma unroll
        for (int lf = 0; lf < 6; ++lf)
            a[lf] = *reinterpret_cast<const float4*>(&s2[(lf*8 + o)*PW + gsw*4]);
        #pragma unroll
        for (int lf = 1; lf < 5; ++lf) {
            float4 b;
            b.x = fmaf(w31, a[lf].x, w30*(a[lf-1].x + a[lf+1].x));
            b.y = fmaf(w31, a[lf].y, w30*(a[lf-1].y + a[lf+1].y));
            b.z = fmaf(w31, a[lf].z, w30*(a[lf-1].z + a[lf+1].z));
            b.w = fmaf(w31, a[lf].w, w30*(a[lf-1].w + a[lf+1].w));
            *reinterpret_cast<float4*>(&s2[(lf*8 + o)*PW + gsw*4]) = b;
        }
    }
    __syncthreads();

    // ---- step 3: 32-tap blur along x, 16 outputs/thread, rolling window ----
    // 32 output rows (lf 1..4, o 0..7) x 14 groups-of-16 = 448 units = 7 waves.
    if (tid < 448) {
        const int r  = tid / 14;           // 0..31
        const int xg = tid - r*14;         // 0..13
        const int lf = 1 + (r >> 3);
        const int o  = r & 7;
        const int fo16 = (4*fg + (r >> 3))*16 + o*2;
        const int x0 = xg * 16;            // output x base (0..208)
        const int rowb = (lf*8 + o)*PW;
        const int g0 = 4*xg;

        float acc[16];
        #pragma unroll
        for (int j = 0; j < 16; ++j) acc[j] = 0.f;

        #pragma unroll
        for (int t = 0; t < 12; ++t) {
            const float4 q = *reinterpret_cast<const float4*>(
                &s2[rowb + swz(g0 + t)*4]);
            #pragma unroll
            for (int e = 0; e < 4; ++e) {
                const int m = 4*t + e;     // window float index 0..47
                const float qv = (e==0)?q.x:(e==1)?q.y:(e==2)?q.z:q.w;
                const int jlo = (m - 31 > 0) ? (m - 31) : 0;
                const int jhi = (m < 15) ? m : 15;
                #pragma unroll
                for (int j = jlo; j <= jhi; ++j)
                    acc[j] = fmaf(ga.wx[m - j], qv, acc[j]);
            }
        }

        float* op = ws + (img*192 + phase)*PLANE + y*SZW + fo16*PLANE + x0;
        #pragma unroll
        for (int s = 0; s < 4; ++s)
            *reinterpret_cast<float4*>(op + 4*s) =
                make_float4(acc[4*s], acc[4*s+1], acc[4*s+2], acc[4*s+3]);
    }
}

__global__ __launch_bounds__(256) void pass2_kernel(const float* __restrict__ ws,
                                                    float* __restrict__ out,
                                                    const GaussArgs ga)
{
    const int c = blockIdx.x;     // 0..767
    const int x = threadIdx.x;    // column
    if (x >= SZW) return;

    const float* col = ws  + c * PLANE + x;
    float*       oc  = out + c * PLANE + x;

    float w[47];
    #pragma unroll
    for (int i = 0; i < 47; ++i) {
        int yy = i - 16;
        w[i] = (yy >= 0 && yy < SZW) ? col[yy*SZW] : 0.f;
    }

    #pragma unroll 1
    for (int y0 = 0; y0 < SZW; y0 += 16) {
        float acc[16];
        #pragma unroll
        for (int j = 0; j < 16; ++j) acc[j] = 0.f;
        #pragma unroll
        for (int k = 0; k < 32; ++k) {
            #pragma unroll
            for (int j = 0; j < 16; ++j)
                acc[j] = fmaf(ga.wx[k], w[j+k], acc[j]);
        }
        #pragma unroll
        for (int j = 0; j < 16; ++j) oc[(y0+j)*SZW] = acc[j];

        #pragma unroll
        for (int i = 0; i < 31; ++i) w[i] = w[i+16];
        #pragma unroll
        for (int i = 0; i < 16; ++i) {
            int yy = y0 + 31 + i;
            w[31+i] = (yy < SZW) ? col[yy*SZW] : 0.f;
        }
    }
}

extern "C" void kernel_launch(void* const* d_in, const int* in_sizes, int n_in,
                              void* d_out, int out_size, void* d_ws, size_t ws_size,
                              hipStream_t stream)
{
    const float* x  = (const float*)d_in[0];
    float*      out = (float*)d_out;
    float*      ws  = (float*)d_ws;   // 768*224*224*4 = 154,140,672 B

    // Host-computed Gaussian weights (double precision, rounded to f32 —
    // matches reference _gauss float64 path).
    GaussArgs ga;
    const double c0 = 1.0 / sqrt(2.0 * 3.14159265358979323846);
    for (int k = 0; k < 32; ++k) {
        double t = -1.0 + 2.0 * (double)k / 31.0;
        ga.wx[k] = (float)(c0 * exp(-t * t / 2.0));
    }
    ga.w31 = (float)c0;
    ga.w30 = (float)(c0 * exp(-0.5));

    dim3 g1(SZW, 6, 4);               // (y, phase*freqgroup, img)
    pass1_kernel<<<g1, 512, 0, stream>>>(x, ws, ga);
    pass2_kernel<<<768, 256, 0, stream>>>(ws, out, ga);
}